// Round 8
// baseline (801.808 us; speedup 1.0000x reference)
//
#include <hip/hip_runtime.h>
#include <hip/hip_bf16.h>
#include <math.h>

#define KD 1024
#define VD 50000
#define BD 2048
#define WDIM 20
#define THRV 1e-10f
#define PI_F 3.14159274101257324f  /* 0x40490FDB — f32(pi) */

#define CH 8192            /* complex elements per chunk (64 KB LDS) */
#define NCH 7              /* 6 full chunks + tail */
#define TAILC 848          /* 50000 - 6*8192 */
#define RPB 4              /* rows per persistent block; grid = KD/RPB = 256 */

// d_out is FLOAT32[2049]: [0..2048) = mu (as float), [2048] = E.

// ---------------------------------------------------------------------------
// Kernel P: b-minor tables. cst[w][b] = (cos,sin)(pi*pos[b][w]);
// idp[j][b] = ids[b][2j] | ids[b][2j+1]<<16. Same trig ops as passing rounds.
// ---------------------------------------------------------------------------
__global__ __launch_bounds__(256) void prep_kernel(
    const float* __restrict__ pos,
    const int*   __restrict__ ids,
    float2* __restrict__ cst,
    unsigned int* __restrict__ idp)
{
    const int b = blockIdx.x * 256 + threadIdx.x;
    if (b >= BD) return;
    int idv[WDIM];
#pragma unroll
    for (int w = 0; w < WDIM; ++w) {
        idv[w] = ids[b * WDIM + w];
        const float pf = __fmul_rn(pos[b * WDIM + w], PI_F);
        cst[w * BD + b] = make_float2(cosf(pf), sinf(pf));
    }
#pragma unroll
    for (int j = 0; j < WDIM / 2; ++j)
        idp[j * BD + b] = (unsigned int)idv[2 * j] |
                          ((unsigned int)idv[2 * j + 1] << 16);
}

// ---------------------------------------------------------------------------
// Kernel B: persistent blocks, 4 rows each. Per chunk: write prefetched regs
// to LDS (+norm2 partial), barrier, ISSUE next chunk's global loads (T14
// async split: they fly during match/score), then predicated LDS match.
// Score math bit-identical to passing rounds (pairwise-8, _rn ops).
// ---------------------------------------------------------------------------
__global__ __launch_bounds__(1024, 4) void row_kernel(
    const float* __restrict__ W,
    const unsigned int* __restrict__ idp,
    const float2* __restrict__ cst,
    float* __restrict__ norm2,
    float* __restrict__ scores)   // [KD][BD]
{
    __shared__ __align__(16) float chunk[CH * 2];   // 64 KB
    __shared__ float sm[16];

    const int t  = threadIdx.x;
    const int k0 = blockIdx.x * RPB;

    // persistent packed ids for b = t and b = t + 1024
    unsigned int idreg[2][WDIM / 2];
#pragma unroll
    for (int j = 0; j < WDIM / 2; ++j) {
        idreg[0][j] = idp[j * BD + t];
        idreg[1][j] = idp[j * BD + t + 1024];
    }

    float gx[2][WDIM], gy[2][WDIM];
#pragma unroll
    for (int w = 0; w < WDIM; ++w) {
        gx[0][w] = 0.f; gy[0][w] = 0.f; gx[1][w] = 0.f; gy[1][w] = 0.f;
    }

    // prefetch chunk 0 of row k0
    float4 pf[4];
    {
        const float4* src = reinterpret_cast<const float4*>(W + (size_t)k0 * (VD * 2));
#pragma unroll
        for (int j = 0; j < 4; ++j) {
            const int i = t + j * 1024;
            if (i < (CH * 2) / 4) pf[j] = src[i];
        }
    }

    for (int r = 0; r < RPB; ++r) {
        const int k = k0 + r;
        float nacc = 0.0f;

        for (int c = 0; c < NCH; ++c) {
            const int nf4 = (c == NCH - 1) ? (TAILC * 2) / 4 : (CH * 2) / 4;

            __syncthreads();   // previous chunk's readers done -> LDS free
            float4* dst = reinterpret_cast<float4*>(chunk);
#pragma unroll
            for (int j = 0; j < 4; ++j) {
                const int i = t + j * 1024;
                if (i < nf4) {
                    const float4 v = pf[j];
                    dst[i] = v;
                    nacc += v.x * v.x + v.y * v.y + v.z * v.z + v.w * v.w;
                }
            }
            __syncthreads();   // chunk visible

            // ---- issue next chunk's loads (flies during match/score) ----
            {
                int nr = r, nc = c + 1;
                if (nc == NCH) { nc = 0; nr = r + 1; }
                if (nr < RPB) {
                    const int nk = k0 + nr;
                    const int nnf4 = (nc == NCH - 1) ? (TAILC * 2) / 4 : (CH * 2) / 4;
                    const float4* src = reinterpret_cast<const float4*>(
                        W + (size_t)nk * (VD * 2) + (size_t)nc * (CH * 2));
#pragma unroll
                    for (int j = 0; j < 4; ++j) {
                        const int i = t + j * 1024;
                        if (i < nnf4) pf[j] = src[i];
                    }
                }
            }

            // ---- predicated match ----
            const int lo = c * CH;
            const unsigned lim = (c == NCH - 1) ? TAILC : CH;
#pragma unroll
            for (int bb = 0; bb < 2; ++bb) {
#pragma unroll
                for (int w = 0; w < WDIM; ++w) {
                    const int id = (int)((idreg[bb][w >> 1] >> ((w & 1) * 16)) & 0xFFFFu);
                    const unsigned off = (unsigned)(id - lo);
                    if (off < lim) {
                        const float2 g = *reinterpret_cast<const float2*>(&chunk[2 * off]);
                        gx[bb][w] = g.x; gy[bb][w] = g.y;
                    }
                }
            }
        }

        // ---- norm2 reduce ----
#pragma unroll
        for (int off = 32; off > 0; off >>= 1) nacc += __shfl_down(nacc, off, 64);
        if ((t & 63) == 0) sm[t >> 6] = nacc;
        __syncthreads();
        if (t == 0) {
            float s = 0.0f;
#pragma unroll
            for (int i = 0; i < 16; ++i) s += sm[i];
            norm2[k] = s;
        }

        // ---- score math (exact numpy pairwise-8 order) ----
#pragma unroll
        for (int bb = 0; bb < 2; ++bb) {
            const int b = t + bb * 1024;
            float phi[WDIM];
#pragma unroll
            for (int w = 0; w < WDIM; ++w) {
                const float2 cs = cst[w * BD + b];
                const float x = gx[bb][w], y = gy[bb][w];
                const float mag = hypotf(x, y);
                const float re  = __fadd_rn(__fmul_rn(x, cs.x), __fmul_rn(y, cs.y));
                const float im  = __fsub_rn(__fmul_rn(y, cs.x), __fmul_rn(x, cs.y));
                phi[w] = __fadd_rn(mag, fabsf(atan2f(im, re)));
            }
            const float r0 = __fadd_rn(phi[0], phi[8]);
            const float r1 = __fadd_rn(phi[1], phi[9]);
            const float r2 = __fadd_rn(phi[2], phi[10]);
            const float r3 = __fadd_rn(phi[3], phi[11]);
            const float r4 = __fadd_rn(phi[4], phi[12]);
            const float r5 = __fadd_rn(phi[5], phi[13]);
            const float r6 = __fadd_rn(phi[6], phi[14]);
            const float r7 = __fadd_rn(phi[7], phi[15]);
            float score = __fadd_rn(__fadd_rn(__fadd_rn(r0, r1), __fadd_rn(r2, r3)),
                                    __fadd_rn(__fadd_rn(r4, r5), __fadd_rn(r6, r7)));
            score = __fadd_rn(score, phi[16]);
            score = __fadd_rn(score, phi[17]);
            score = __fadd_rn(score, phi[18]);
            score = __fadd_rn(score, phi[19]);
            scores[(size_t)k * BD + b] = score;
        }
    }
}

// ---------------------------------------------------------------------------
// Kernel C: argmax over k per batch (coalesced). Strict >, tie -> smallest k.
// ---------------------------------------------------------------------------
__global__ __launch_bounds__(256) void argmax_kernel(
    const float* __restrict__ scores,
    float* __restrict__ out,
    int*   __restrict__ mu_int)
{
    const int b = blockIdx.x * 256 + threadIdx.x;
    float best = -3.402823466e+38f;
    int   bi   = 0;
    for (int k = 0; k < KD; ++k) {
        const float v = scores[(size_t)k * BD + b];
        if (v > best) { best = v; bi = k; }
    }
    mu_int[b] = bi;
    out[b] = (float)bi;
}

// ---------------------------------------------------------------------------
// Kernel D: per-batch energy contribution
// ---------------------------------------------------------------------------
__global__ __launch_bounds__(64) void e_kernel(
    const float* __restrict__ W,
    const float* __restrict__ Ps,
    const float* __restrict__ pos,
    const int*   __restrict__ ids,
    const int*   __restrict__ mu_int,
    const float* __restrict__ norm2,
    float* __restrict__ contrib)
{
    const int b = blockIdx.x;
    const int t = threadIdx.x;
    const int mu = mu_int[b];
    const float* Wm = W + (size_t)mu * (VD * 2);

    float loc_abs = 0.0f, loc_phi = 0.0f;
    if (t < WDIM) {
        const int id = ids[b * WDIM + t];
        const float P = Ps[b * WDIM + t];
        const float pf = __fmul_rn(pos[b * WDIM + t], PI_F);
        const float c = cosf(pf), s = sinf(pf);
        const float2 g = *reinterpret_cast<const float2*>(Wm + 2 * (size_t)id);
        float re = P * (g.x * c + g.y * s);
        float im = P * (g.y * c - g.x * s);
        if (re < THRV && re > -THRV) re = THRV;
        if (im < THRV && im > -THRV) im = THRV;
        loc_abs = sqrtf(re * re + im * im);
        loc_phi = fabsf(atan2f(im, re)) * P;
    }
#pragma unroll
    for (int off = 32; off > 0; off >>= 1) {
        loc_abs += __shfl_down(loc_abs, off, 64);
        loc_phi += __shfl_down(loc_phi, off, 64);
    }
    if (t == 0) {
        const float den = sqrtf(norm2[mu]);
        contrib[b] = loc_abs / den + loc_phi;
    }
}

// ---------------------------------------------------------------------------
// Kernel E: deterministic final reduction (f64 accum), E -> out[2048]
// ---------------------------------------------------------------------------
__global__ __launch_bounds__(256) void finalize_kernel(
    const float* __restrict__ contrib,
    float* __restrict__ out)
{
    __shared__ double sm[4];
    double acc = 0.0;
    for (int i = threadIdx.x; i < BD; i += 256) acc += (double)contrib[i];
#pragma unroll
    for (int off = 32; off > 0; off >>= 1) acc += __shfl_down(acc, off, 64);
    if ((threadIdx.x & 63) == 0) sm[threadIdx.x >> 6] = acc;
    __syncthreads();
    if (threadIdx.x == 0) {
        double s = sm[0] + sm[1] + sm[2] + sm[3];
        out[BD] = (float)(-s);
    }
}

// ---------------------------------------------------------------------------
// Fallback (round-5 passing path) if ws_size is too small
// ---------------------------------------------------------------------------
__global__ __launch_bounds__(1024) void scores_kernel_fb(
    const float* __restrict__ W,
    const float* __restrict__ pos,
    const int*   __restrict__ ids,
    float* __restrict__ out,
    int* __restrict__ mu_int)
{
    __shared__ int   s_id[WDIM];
    __shared__ float s_c[WDIM];
    __shared__ float s_s[WDIM];
    __shared__ float r_val[16];
    __shared__ int   r_idx[16];

    const int b = blockIdx.x;
    const int t = threadIdx.x;

    if (t < WDIM) {
        s_id[t] = ids[b * WDIM + t];
        const float pf = __fmul_rn(pos[b * WDIM + t], PI_F);
        s_c[t] = cosf(pf);
        s_s[t] = sinf(pf);
    }
    __syncthreads();

    const float* Wk = W + (size_t)t * (VD * 2);
    float phi[WDIM];
#pragma unroll
    for (int w = 0; w < WDIM; ++w) {
        const float2 g = *reinterpret_cast<const float2*>(Wk + 2 * (size_t)s_id[w]);
        const float c = s_c[w], s = s_s[w];
        const float mag = hypotf(g.x, g.y);
        const float re = __fadd_rn(__fmul_rn(g.x, c), __fmul_rn(g.y, s));
        const float im = __fsub_rn(__fmul_rn(g.y, c), __fmul_rn(g.x, s));
        phi[w] = __fadd_rn(mag, fabsf(atan2f(im, re)));
    }
    const float r0 = __fadd_rn(phi[0], phi[8]);
    const float r1 = __fadd_rn(phi[1], phi[9]);
    const float r2 = __fadd_rn(phi[2], phi[10]);
    const float r3 = __fadd_rn(phi[3], phi[11]);
    const float r4 = __fadd_rn(phi[4], phi[12]);
    const float r5 = __fadd_rn(phi[5], phi[13]);
    const float r6 = __fadd_rn(phi[6], phi[14]);
    const float r7 = __fadd_rn(phi[7], phi[15]);
    float score = __fadd_rn(__fadd_rn(__fadd_rn(r0, r1), __fadd_rn(r2, r3)),
                            __fadd_rn(__fadd_rn(r4, r5), __fadd_rn(r6, r7)));
    score = __fadd_rn(score, phi[16]);
    score = __fadd_rn(score, phi[17]);
    score = __fadd_rn(score, phi[18]);
    score = __fadd_rn(score, phi[19]);

    float v = score; int vi = t;
#pragma unroll
    for (int off = 32; off > 0; off >>= 1) {
        float ov = __shfl_down(v, off, 64);
        int   oi = __shfl_down(vi, off, 64);
        if (ov > v || (ov == v && oi < vi)) { v = ov; vi = oi; }
    }
    if ((t & 63) == 0) { r_val[t >> 6] = v; r_idx[t >> 6] = vi; }
    __syncthreads();
    if (t == 0) {
        float bv = r_val[0]; int bi = r_idx[0];
#pragma unroll
        for (int i = 1; i < 16; ++i) {
            if (r_val[i] > bv || (r_val[i] == bv && r_idx[i] < bi)) {
                bv = r_val[i]; bi = r_idx[i];
            }
        }
        mu_int[b] = bi;
        out[b] = (float)bi;
    }
}

__global__ __launch_bounds__(512) void norm_kernel_fb(
    const float* __restrict__ W,
    float* __restrict__ norm2)
{
    const int k = blockIdx.x;
    const float4* row = reinterpret_cast<const float4*>(W + (size_t)k * (VD * 2));
    const int n4 = (VD * 2) / 4;
    float acc = 0.0f;
    for (int i = threadIdx.x; i < n4; i += 512) {
        float4 v = row[i];
        acc += v.x * v.x + v.y * v.y + v.z * v.z + v.w * v.w;
    }
    __shared__ float sm[8];
#pragma unroll
    for (int off = 32; off > 0; off >>= 1) acc += __shfl_down(acc, off, 64);
    if ((threadIdx.x & 63) == 0) sm[threadIdx.x >> 6] = acc;
    __syncthreads();
    if (threadIdx.x == 0) {
        float s = 0.0f;
#pragma unroll
        for (int i = 0; i < 8; ++i) s += sm[i];
        norm2[k] = s;
    }
}

extern "C" void kernel_launch(void* const* d_in, const int* in_sizes, int n_in,
                              void* d_out, int out_size, void* d_ws, size_t ws_size,
                              hipStream_t stream) {
    const float* W   = (const float*)d_in[0];  // (K, V, 2) fp32
    const float* Ps  = (const float*)d_in[1];  // (B, WD) fp32
    const float* pos = (const float*)d_in[2];  // (B, WD) fp32
    const int*   ids = (const int*)d_in[3];    // (B, WD) int32

    float* out = (float*)d_out;                // float32[2049]

    // ws layout
    float2*       cst     = (float2*)d_ws;                         // WD*BD float2
    unsigned int* idp     = (unsigned int*)(cst + WDIM * BD);      // (WD/2)*BD u32
    float*        norm2   = (float*)(idp + (WDIM / 2) * BD);       // KD
    float*        contrib = norm2 + KD;                            // BD
    int*          mu_int  = (int*)(contrib + BD);                  // BD
    float*        scores  = (float*)(mu_int + BD);                 // KD*BD
    const size_t need = (size_t)(WDIM * BD * 2 + (WDIM / 2) * BD + KD + 2 * BD) * 4
                      + (size_t)KD * BD * 4;

    if (ws_size >= need) {
        prep_kernel<<<(BD + 255) / 256, 256, 0, stream>>>(pos, ids, cst, idp);
        row_kernel<<<KD / RPB, 1024, 0, stream>>>(W, idp, cst, norm2, scores);
        argmax_kernel<<<BD / 256, 256, 0, stream>>>(scores, out, mu_int);
    } else {
        scores_kernel_fb<<<BD, 1024, 0, stream>>>(W, pos, ids, out, mu_int);
        norm_kernel_fb<<<KD, 512, 0, stream>>>(W, norm2);
    }
    e_kernel<<<BD, 64, 0, stream>>>(W, Ps, pos, ids, mu_int, norm2, contrib);
    finalize_kernel<<<1, 256, 0, stream>>>(contrib, out);
}

// Round 9
// 405.213 us; speedup vs baseline: 1.9787x; 1.9787x over previous
//
#include <hip/hip_runtime.h>
#include <hip/hip_bf16.h>
#include <math.h>

#define KD 1024
#define VD 50000
#define BD 2048
#define WDIM 20
#define THRV 1e-10f
#define PI_F 3.14159274101257324f  /* 0x40490FDB — f32(pi) */

#define CH 8192            /* complex elements per chunk (64 KB LDS) */
#define NCH 7              /* 6 full chunks + tail */
#define TAILC 848          /* 50000 - 6*8192 */

// d_out is FLOAT32[2049]: [0..2048) = mu (as float), [2048] = E.

#define WAITVM(N) asm volatile("s_waitcnt vmcnt(" #N ")" ::: "memory")

typedef const __attribute__((address_space(1))) void* gas1_t;
typedef __attribute__((address_space(3))) void* las3_t;

__device__ __forceinline__ void gload16(const float4* g, float4* l) {
    // direct global->LDS DMA, 16B per lane; LDS dest = wave-uniform base + lane*16
    __builtin_amdgcn_global_load_lds((gas1_t)g, (las3_t)l, 16, 0, 0);
}

// ---------------------------------------------------------------------------
// Kernel P: b-minor tables. cst[w][b] = (cos,sin)(pi*pos[b][w]);
// idp[j][b] = ids[b][2j] | ids[b][2j+1]<<16. Same trig ops as passing rounds.
// ---------------------------------------------------------------------------
__global__ __launch_bounds__(256) void prep_kernel(
    const float* __restrict__ pos,
    const int*   __restrict__ ids,
    float2* __restrict__ cst,
    unsigned int* __restrict__ idp)
{
    const int b = blockIdx.x * 256 + threadIdx.x;
    if (b >= BD) return;
    int idv[WDIM];
#pragma unroll
    for (int w = 0; w < WDIM; ++w) {
        idv[w] = ids[b * WDIM + w];
        const float pf = __fmul_rn(pos[b * WDIM + w], PI_F);
        cst[w * BD + b] = make_float2(cosf(pf), sinf(pf));
    }
#pragma unroll
    for (int j = 0; j < WDIM / 2; ++j)
        idp[j * BD + b] = (unsigned int)idv[2 * j] |
                          ((unsigned int)idv[2 * j + 1] << 16);
}

// ---------------------------------------------------------------------------
// Kernel B: one block per row. Double-buffered 64KB LDS chunks filled by
// global_load_lds (no data VGPRs -> no spill, unlike round 8). Counted
// vmcnt(4) keeps next chunk's loads in flight during the match phase.
// Score math bit-identical to passing rounds (pairwise-8, _rn ops).
// ---------------------------------------------------------------------------
__global__ __launch_bounds__(1024, 4) void row_kernel(
    const float* __restrict__ W,
    const unsigned int* __restrict__ idp,
    const float2* __restrict__ cst,
    float* __restrict__ norm2,
    float* __restrict__ scores)   // [KD][BD]
{
    __shared__ __align__(16) float4 buf[2][(CH * 2) / 4];   // 2 x 64 KB
    __shared__ float sm[16];

    const int t = threadIdx.x;
    const int k = blockIdx.x;
    const float* Wk = W + (size_t)k * (VD * 2);

    // packed ids for b = t and b = t + 1024
    unsigned int idreg[2][WDIM / 2];
#pragma unroll
    for (int j = 0; j < WDIM / 2; ++j) {
        idreg[0][j] = idp[j * BD + t];
        idreg[1][j] = idp[j * BD + t + 1024];
    }

    float gx[2][WDIM], gy[2][WDIM];
#pragma unroll
    for (int w = 0; w < WDIM; ++w) {
        gx[0][w] = 0.f; gy[0][w] = 0.f; gx[1][w] = 0.f; gy[1][w] = 0.f;
    }

    // prologue: issue chunk 0 -> buf[0]
    {
        const float4* src = reinterpret_cast<const float4*>(Wk);
#pragma unroll
        for (int j = 0; j < 4; ++j)
            gload16(src + t + j * 1024, &buf[0][t + j * 1024]);
    }

    float nacc = 0.0f;

    for (int c = 0; c < NCH; ++c) {
        const int p = c & 1;
        const bool istail = (c == NCH - 1);

        __builtin_amdgcn_s_barrier();   // all readers of buf[p^1] done

        if (c + 1 < NCH - 1) {
            // issue next full chunk -> buf[p^1]; it flies during this match
            const float4* src = reinterpret_cast<const float4*>(
                Wk + (size_t)(c + 1) * (CH * 2));
#pragma unroll
            for (int j = 0; j < 4; ++j)
                gload16(src + t + j * 1024, &buf[p ^ 1][t + j * 1024]);
            WAITVM(4);                  // chunk c landed; chunk c+1 in flight
        } else if (c + 1 == NCH - 1) {
            WAITVM(0);                  // next is tail (loaded sync below)
        } else {
            // c IS the tail: load it synchronously into buf[p]
            const float4* src = reinterpret_cast<const float4*>(
                Wk + (size_t)c * (CH * 2));
            if (t < (TAILC * 2) / 4)
                gload16(src + t, &buf[p][t]);
            WAITVM(0);
        }

        __builtin_amdgcn_s_barrier();   // chunk c visible to all

        // ---- norm2 partial from LDS ----
        const int nf4 = istail ? (TAILC * 2) / 4 : (CH * 2) / 4;
#pragma unroll
        for (int j = 0; j < 4; ++j) {
            const int i = t + j * 1024;
            if (i < nf4) {
                const float4 v = buf[p][i];
                nacc += v.x * v.x + v.y * v.y + v.z * v.z + v.w * v.w;
            }
        }

        // ---- predicated match ----
        const float* ch = reinterpret_cast<const float*>(buf[p]);
        const int lo = c * CH;
        const unsigned lim = istail ? TAILC : CH;
#pragma unroll
        for (int bb = 0; bb < 2; ++bb) {
#pragma unroll
            for (int w = 0; w < WDIM; ++w) {
                const int id = (int)((idreg[bb][w >> 1] >> ((w & 1) * 16)) & 0xFFFFu);
                const unsigned off = (unsigned)(id - lo);
                if (off < lim) {
                    gx[bb][w] = ch[2 * off];
                    gy[bb][w] = ch[2 * off + 1];
                }
            }
        }
    }

    // ---- norm2 reduce ----
#pragma unroll
    for (int off = 32; off > 0; off >>= 1) nacc += __shfl_down(nacc, off, 64);
    if ((t & 63) == 0) sm[t >> 6] = nacc;
    __syncthreads();
    if (t == 0) {
        float s = 0.0f;
#pragma unroll
        for (int i = 0; i < 16; ++i) s += sm[i];
        norm2[k] = s;
    }

    // ---- score math (exact numpy pairwise-8 order) ----
#pragma unroll
    for (int bb = 0; bb < 2; ++bb) {
        const int b = t + bb * 1024;
        float phi[WDIM];
#pragma unroll
        for (int w = 0; w < WDIM; ++w) {
            const float2 cs = cst[w * BD + b];
            const float x = gx[bb][w], y = gy[bb][w];
            const float mag = hypotf(x, y);
            const float re  = __fadd_rn(__fmul_rn(x, cs.x), __fmul_rn(y, cs.y));
            const float im  = __fsub_rn(__fmul_rn(y, cs.x), __fmul_rn(x, cs.y));
            phi[w] = __fadd_rn(mag, fabsf(atan2f(im, re)));
        }
        const float r0 = __fadd_rn(phi[0], phi[8]);
        const float r1 = __fadd_rn(phi[1], phi[9]);
        const float r2 = __fadd_rn(phi[2], phi[10]);
        const float r3 = __fadd_rn(phi[3], phi[11]);
        const float r4 = __fadd_rn(phi[4], phi[12]);
        const float r5 = __fadd_rn(phi[5], phi[13]);
        const float r6 = __fadd_rn(phi[6], phi[14]);
        const float r7 = __fadd_rn(phi[7], phi[15]);
        float score = __fadd_rn(__fadd_rn(__fadd_rn(r0, r1), __fadd_rn(r2, r3)),
                                __fadd_rn(__fadd_rn(r4, r5), __fadd_rn(r6, r7)));
        score = __fadd_rn(score, phi[16]);
        score = __fadd_rn(score, phi[17]);
        score = __fadd_rn(score, phi[18]);
        score = __fadd_rn(score, phi[19]);
        scores[(size_t)k * BD + b] = score;
    }
}

// ---------------------------------------------------------------------------
// Kernel C: argmax over k per batch (coalesced). Strict >, tie -> smallest k.
// ---------------------------------------------------------------------------
__global__ __launch_bounds__(256) void argmax_kernel(
    const float* __restrict__ scores,
    float* __restrict__ out,
    int*   __restrict__ mu_int)
{
    const int b = blockIdx.x * 256 + threadIdx.x;
    float best = -3.402823466e+38f;
    int   bi   = 0;
    for (int k = 0; k < KD; ++k) {
        const float v = scores[(size_t)k * BD + b];
        if (v > best) { best = v; bi = k; }
    }
    mu_int[b] = bi;
    out[b] = (float)bi;
}

// ---------------------------------------------------------------------------
// Kernel D: per-batch energy contribution
// ---------------------------------------------------------------------------
__global__ __launch_bounds__(64) void e_kernel(
    const float* __restrict__ W,
    const float* __restrict__ Ps,
    const float* __restrict__ pos,
    const int*   __restrict__ ids,
    const int*   __restrict__ mu_int,
    const float* __restrict__ norm2,
    float* __restrict__ contrib)
{
    const int b = blockIdx.x;
    const int t = threadIdx.x;
    const int mu = mu_int[b];
    const float* Wm = W + (size_t)mu * (VD * 2);

    float loc_abs = 0.0f, loc_phi = 0.0f;
    if (t < WDIM) {
        const int id = ids[b * WDIM + t];
        const float P = Ps[b * WDIM + t];
        const float pf = __fmul_rn(pos[b * WDIM + t], PI_F);
        const float c = cosf(pf), s = sinf(pf);
        const float2 g = *reinterpret_cast<const float2*>(Wm + 2 * (size_t)id);
        float re = P * (g.x * c + g.y * s);
        float im = P * (g.y * c - g.x * s);
        if (re < THRV && re > -THRV) re = THRV;
        if (im < THRV && im > -THRV) im = THRV;
        loc_abs = sqrtf(re * re + im * im);
        loc_phi = fabsf(atan2f(im, re)) * P;
    }
#pragma unroll
    for (int off = 32; off > 0; off >>= 1) {
        loc_abs += __shfl_down(loc_abs, off, 64);
        loc_phi += __shfl_down(loc_phi, off, 64);
    }
    if (t == 0) {
        const float den = sqrtf(norm2[mu]);
        contrib[b] = loc_abs / den + loc_phi;
    }
}

// ---------------------------------------------------------------------------
// Kernel E: deterministic final reduction (f64 accum), E -> out[2048]
// ---------------------------------------------------------------------------
__global__ __launch_bounds__(256) void finalize_kernel(
    const float* __restrict__ contrib,
    float* __restrict__ out)
{
    __shared__ double sm[4];
    double acc = 0.0;
    for (int i = threadIdx.x; i < BD; i += 256) acc += (double)contrib[i];
#pragma unroll
    for (int off = 32; off > 0; off >>= 1) acc += __shfl_down(acc, off, 64);
    if ((threadIdx.x & 63) == 0) sm[threadIdx.x >> 6] = acc;
    __syncthreads();
    if (threadIdx.x == 0) {
        double s = sm[0] + sm[1] + sm[2] + sm[3];
        out[BD] = (float)(-s);
    }
}

// ---------------------------------------------------------------------------
// Fallback (round-5 passing path) if ws_size is too small
// ---------------------------------------------------------------------------
__global__ __launch_bounds__(1024) void scores_kernel_fb(
    const float* __restrict__ W,
    const float* __restrict__ pos,
    const int*   __restrict__ ids,
    float* __restrict__ out,
    int* __restrict__ mu_int)
{
    __shared__ int   s_id[WDIM];
    __shared__ float s_c[WDIM];
    __shared__ float s_s[WDIM];
    __shared__ float r_val[16];
    __shared__ int   r_idx[16];

    const int b = blockIdx.x;
    const int t = threadIdx.x;

    if (t < WDIM) {
        s_id[t] = ids[b * WDIM + t];
        const float pf = __fmul_rn(pos[b * WDIM + t], PI_F);
        s_c[t] = cosf(pf);
        s_s[t] = sinf(pf);
    }
    __syncthreads();

    const float* Wk = W + (size_t)t * (VD * 2);
    float phi[WDIM];
#pragma unroll
    for (int w = 0; w < WDIM; ++w) {
        const float2 g = *reinterpret_cast<const float2*>(Wk + 2 * (size_t)s_id[w]);
        const float c = s_c[w], s = s_s[w];
        const float mag = hypotf(g.x, g.y);
        const float re = __fadd_rn(__fmul_rn(g.x, c), __fmul_rn(g.y, s));
        const float im = __fsub_rn(__fmul_rn(g.y, c), __fmul_rn(g.x, s));
        phi[w] = __fadd_rn(mag, fabsf(atan2f(im, re)));
    }
    const float r0 = __fadd_rn(phi[0], phi[8]);
    const float r1 = __fadd_rn(phi[1], phi[9]);
    const float r2 = __fadd_rn(phi[2], phi[10]);
    const float r3 = __fadd_rn(phi[3], phi[11]);
    const float r4 = __fadd_rn(phi[4], phi[12]);
    const float r5 = __fadd_rn(phi[5], phi[13]);
    const float r6 = __fadd_rn(phi[6], phi[14]);
    const float r7 = __fadd_rn(phi[7], phi[15]);
    float score = __fadd_rn(__fadd_rn(__fadd_rn(r0, r1), __fadd_rn(r2, r3)),
                            __fadd_rn(__fadd_rn(r4, r5), __fadd_rn(r6, r7)));
    score = __fadd_rn(score, phi[16]);
    score = __fadd_rn(score, phi[17]);
    score = __fadd_rn(score, phi[18]);
    score = __fadd_rn(score, phi[19]);

    float v = score; int vi = t;
#pragma unroll
    for (int off = 32; off > 0; off >>= 1) {
        float ov = __shfl_down(v, off, 64);
        int   oi = __shfl_down(vi, off, 64);
        if (ov > v || (ov == v && oi < vi)) { v = ov; vi = oi; }
    }
    if ((t & 63) == 0) { r_val[t >> 6] = v; r_idx[t >> 6] = vi; }
    __syncthreads();
    if (t == 0) {
        float bv = r_val[0]; int bi = r_idx[0];
#pragma unroll
        for (int i = 1; i < 16; ++i) {
            if (r_val[i] > bv || (r_val[i] == bv && r_idx[i] < bi)) {
                bv = r_val[i]; bi = r_idx[i];
            }
        }
        mu_int[b] = bi;
        out[b] = (float)bi;
    }
}

__global__ __launch_bounds__(512) void norm_kernel_fb(
    const float* __restrict__ W,
    float* __restrict__ norm2)
{
    const int k = blockIdx.x;
    const float4* row = reinterpret_cast<const float4*>(W + (size_t)k * (VD * 2));
    const int n4 = (VD * 2) / 4;
    float acc = 0.0f;
    for (int i = threadIdx.x; i < n4; i += 512) {
        float4 v = row[i];
        acc += v.x * v.x + v.y * v.y + v.z * v.z + v.w * v.w;
    }
    __shared__ float sm[8];
#pragma unroll
    for (int off = 32; off > 0; off >>= 1) acc += __shfl_down(acc, off, 64);
    if ((threadIdx.x & 63) == 0) sm[threadIdx.x >> 6] = acc;
    __syncthreads();
    if (threadIdx.x == 0) {
        float s = 0.0f;
#pragma unroll
        for (int i = 0; i < 8; ++i) s += sm[i];
        norm2[k] = s;
    }
}

extern "C" void kernel_launch(void* const* d_in, const int* in_sizes, int n_in,
                              void* d_out, int out_size, void* d_ws, size_t ws_size,
                              hipStream_t stream) {
    const float* W   = (const float*)d_in[0];  // (K, V, 2) fp32
    const float* Ps  = (const float*)d_in[1];  // (B, WD) fp32
    const float* pos = (const float*)d_in[2];  // (B, WD) fp32
    const int*   ids = (const int*)d_in[3];    // (B, WD) int32

    float* out = (float*)d_out;                // float32[2049]

    // ws layout
    float2*       cst     = (float2*)d_ws;                         // WD*BD float2
    unsigned int* idp     = (unsigned int*)(cst + WDIM * BD);      // (WD/2)*BD u32
    float*        norm2   = (float*)(idp + (WDIM / 2) * BD);       // KD
    float*        contrib = norm2 + KD;                            // BD
    int*          mu_int  = (int*)(contrib + BD);                  // BD
    float*        scores  = (float*)(mu_int + BD);                 // KD*BD
    const size_t need = (size_t)(WDIM * BD * 2 + (WDIM / 2) * BD + KD + 2 * BD) * 4
                      + (size_t)KD * BD * 4;

    if (ws_size >= need) {
        prep_kernel<<<(BD + 255) / 256, 256, 0, stream>>>(pos, ids, cst, idp);
        row_kernel<<<KD, 1024, 0, stream>>>(W, idp, cst, norm2, scores);
        argmax_kernel<<<BD / 256, 256, 0, stream>>>(scores, out, mu_int);
    } else {
        scores_kernel_fb<<<BD, 1024, 0, stream>>>(W, pos, ids, out, mu_int);
        norm_kernel_fb<<<KD, 512, 0, stream>>>(W, norm2);
    }
    e_kernel<<<BD, 64, 0, stream>>>(W, Ps, pos, ids, mu_int, norm2, contrib);
    finalize_kernel<<<1, 256, 0, stream>>>(contrib, out);
}

// Round 10
// 344.581 us; speedup vs baseline: 2.3269x; 1.1760x over previous
//
#include <hip/hip_runtime.h>
#include <hip/hip_bf16.h>
#include <math.h>

#define KD 1024
#define VD 50000
#define BD 2048
#define WDIM 20
#define THRV 1e-10f
#define PI_F 3.14159274101257324f  /* 0x40490FDB — f32(pi) */

#define CH 8192            /* complex elements per chunk (64 KB LDS) */
#define NCH 7              /* 6 full chunks + tail */
#define TAILC 848          /* 50000 - 6*8192 */

// d_out is FLOAT32[2049]: [0..2048) = mu (as float), [2048] = E.

#define WAITVM(N) asm volatile("s_waitcnt vmcnt(" #N ")" ::: "memory")

typedef const __attribute__((address_space(1))) void* gas1_t;
typedef __attribute__((address_space(3))) void* las3_t;

__device__ __forceinline__ void gload16(const float4* g, float4* l) {
    __builtin_amdgcn_global_load_lds((gas1_t)g, (las3_t)l, 16, 0, 0);
}

// ---------------------------------------------------------------------------
// Kernel P: b-minor tables. cst[w][b] = (cos,sin)(pi*pos[b][w]);
// idp[j][b] = ids[b][2j] | ids[b][2j+1]<<16. Same trig ops as passing rounds.
// ---------------------------------------------------------------------------
__global__ __launch_bounds__(256) void prep_kernel(
    const float* __restrict__ pos,
    const int*   __restrict__ ids,
    float2* __restrict__ cst,
    unsigned int* __restrict__ idp)
{
    const int b = blockIdx.x * 256 + threadIdx.x;
    if (b >= BD) return;
    int idv[WDIM];
#pragma unroll
    for (int w = 0; w < WDIM; ++w) {
        idv[w] = ids[b * WDIM + w];
        const float pf = __fmul_rn(pos[b * WDIM + w], PI_F);
        cst[w * BD + b] = make_float2(cosf(pf), sinf(pf));
    }
#pragma unroll
    for (int j = 0; j < WDIM / 2; ++j)
        idp[j * BD + b] = (unsigned int)idv[2 * j] |
                          ((unsigned int)idv[2 * j + 1] << 16);
}

// ---------------------------------------------------------------------------
// Kernel B: grid 2048 = (row k) x (b-half). Each block streams the full row
// via double-buffered global_load_lds (round-9 pipeline, validated); each
// THREAD owns ONE batch b -> gx/gy = 40 floats -> ~80 VGPR, no scratch
// (round 8/9 lesson: 80-float state at 1024 threads spills, 522 MB writes).
// Pair-swizzle puts both halves of row k on the same XCD in adjacent slots
// so the twin's stream hits L2. Score math bit-identical to rounds 5-9.
// ---------------------------------------------------------------------------
__global__ __launch_bounds__(1024, 4) void row_kernel(
    const float* __restrict__ W,
    const unsigned int* __restrict__ idp,
    const float2* __restrict__ cst,
    float* __restrict__ norm2,
    float* __restrict__ scores)   // [KD][BD]
{
    __shared__ __align__(16) float4 buf[2][(CH * 2) / 4];   // 2 x 64 KB
    __shared__ float sm[16];

    const int t = threadIdx.x;
    // pair-swizzle: g = xcd + 8*slot; k = (slot/2)*8 + xcd; half = slot%2
    const int g    = blockIdx.x;
    const int xcd  = g & 7;
    const int slot = g >> 3;
    const int k    = (slot >> 1) * 8 + xcd;
    const int half = slot & 1;
    const int b    = half * 1024 + t;

    const float* Wk = W + (size_t)k * (VD * 2);

    // packed ids for this thread's single b
    unsigned int idreg[WDIM / 2];
#pragma unroll
    for (int j = 0; j < WDIM / 2; ++j) idreg[j] = idp[j * BD + b];

    float gx[WDIM], gy[WDIM];
#pragma unroll
    for (int w = 0; w < WDIM; ++w) { gx[w] = 0.f; gy[w] = 0.f; }

    // prologue: issue chunk 0 -> buf[0]
    {
        const float4* src = reinterpret_cast<const float4*>(Wk);
#pragma unroll
        for (int j = 0; j < 4; ++j)
            gload16(src + t + j * 1024, &buf[0][t + j * 1024]);
    }

    float nacc = 0.0f;

    for (int c = 0; c < NCH; ++c) {
        const int p = c & 1;
        const bool istail = (c == NCH - 1);

        __builtin_amdgcn_s_barrier();   // all readers of buf[p^1] done

        if (c + 1 < NCH - 1) {
            const float4* src = reinterpret_cast<const float4*>(
                Wk + (size_t)(c + 1) * (CH * 2));
#pragma unroll
            for (int j = 0; j < 4; ++j)
                gload16(src + t + j * 1024, &buf[p ^ 1][t + j * 1024]);
            WAITVM(4);                  // chunk c landed; chunk c+1 in flight
        } else if (c + 1 == NCH - 1) {
            WAITVM(0);                  // next is tail (loaded sync below)
        } else {
            const float4* src = reinterpret_cast<const float4*>(
                Wk + (size_t)c * (CH * 2));
            if (t < (TAILC * 2) / 4)
                gload16(src + t, &buf[p][t]);
            WAITVM(0);
        }

        __builtin_amdgcn_s_barrier();   // chunk c visible to all

        // ---- norm2 partial from LDS ----
        const int nf4 = istail ? (TAILC * 2) / 4 : (CH * 2) / 4;
#pragma unroll
        for (int j = 0; j < 4; ++j) {
            const int i = t + j * 1024;
            if (i < nf4) {
                const float4 v = buf[p][i];
                nacc += v.x * v.x + v.y * v.y + v.z * v.z + v.w * v.w;
            }
        }

        // ---- predicated match (one b per thread) ----
        const float* ch = reinterpret_cast<const float*>(buf[p]);
        const int lo = c * CH;
        const unsigned lim = istail ? TAILC : CH;
#pragma unroll
        for (int w = 0; w < WDIM; ++w) {
            const int id = (int)((idreg[w >> 1] >> ((w & 1) * 16)) & 0xFFFFu);
            const unsigned off = (unsigned)(id - lo);
            if (off < lim) {
                gx[w] = ch[2 * off];
                gy[w] = ch[2 * off + 1];
            }
        }
    }

    // ---- norm2 reduce (write once, from half 0) ----
#pragma unroll
    for (int off = 32; off > 0; off >>= 1) nacc += __shfl_down(nacc, off, 64);
    if ((t & 63) == 0) sm[t >> 6] = nacc;
    __syncthreads();
    if (t == 0 && half == 0) {
        float s = 0.0f;
#pragma unroll
        for (int i = 0; i < 16; ++i) s += sm[i];
        norm2[k] = s;
    }

    // ---- score math (exact numpy pairwise-8 order) ----
    {
        float phi[WDIM];
#pragma unroll
        for (int w = 0; w < WDIM; ++w) {
            const float2 cs = cst[w * BD + b];
            const float x = gx[w], y = gy[w];
            const float mag = hypotf(x, y);
            const float re  = __fadd_rn(__fmul_rn(x, cs.x), __fmul_rn(y, cs.y));
            const float im  = __fsub_rn(__fmul_rn(y, cs.x), __fmul_rn(x, cs.y));
            phi[w] = __fadd_rn(mag, fabsf(atan2f(im, re)));
        }
        const float r0 = __fadd_rn(phi[0], phi[8]);
        const float r1 = __fadd_rn(phi[1], phi[9]);
        const float r2 = __fadd_rn(phi[2], phi[10]);
        const float r3 = __fadd_rn(phi[3], phi[11]);
        const float r4 = __fadd_rn(phi[4], phi[12]);
        const float r5 = __fadd_rn(phi[5], phi[13]);
        const float r6 = __fadd_rn(phi[6], phi[14]);
        const float r7 = __fadd_rn(phi[7], phi[15]);
        float score = __fadd_rn(__fadd_rn(__fadd_rn(r0, r1), __fadd_rn(r2, r3)),
                                __fadd_rn(__fadd_rn(r4, r5), __fadd_rn(r6, r7)));
        score = __fadd_rn(score, phi[16]);
        score = __fadd_rn(score, phi[17]);
        score = __fadd_rn(score, phi[18]);
        score = __fadd_rn(score, phi[19]);
        scores[(size_t)k * BD + b] = score;
    }
}

// ---------------------------------------------------------------------------
// Kernel C: argmax over k per batch (coalesced). Strict >, tie -> smallest k.
// ---------------------------------------------------------------------------
__global__ __launch_bounds__(256) void argmax_kernel(
    const float* __restrict__ scores,
    float* __restrict__ out,
    int*   __restrict__ mu_int)
{
    const int b = blockIdx.x * 256 + threadIdx.x;
    float best = -3.402823466e+38f;
    int   bi   = 0;
    for (int k = 0; k < KD; ++k) {
        const float v = scores[(size_t)k * BD + b];
        if (v > best) { best = v; bi = k; }
    }
    mu_int[b] = bi;
    out[b] = (float)bi;
}

// ---------------------------------------------------------------------------
// Kernel D: per-batch energy contribution
// ---------------------------------------------------------------------------
__global__ __launch_bounds__(64) void e_kernel(
    const float* __restrict__ W,
    const float* __restrict__ Ps,
    const float* __restrict__ pos,
    const int*   __restrict__ ids,
    const int*   __restrict__ mu_int,
    const float* __restrict__ norm2,
    float* __restrict__ contrib)
{
    const int b = blockIdx.x;
    const int t = threadIdx.x;
    const int mu = mu_int[b];
    const float* Wm = W + (size_t)mu * (VD * 2);

    float loc_abs = 0.0f, loc_phi = 0.0f;
    if (t < WDIM) {
        const int id = ids[b * WDIM + t];
        const float P = Ps[b * WDIM + t];
        const float pf = __fmul_rn(pos[b * WDIM + t], PI_F);
        const float c = cosf(pf), s = sinf(pf);
        const float2 g = *reinterpret_cast<const float2*>(Wm + 2 * (size_t)id);
        float re = P * (g.x * c + g.y * s);
        float im = P * (g.y * c - g.x * s);
        if (re < THRV && re > -THRV) re = THRV;
        if (im < THRV && im > -THRV) im = THRV;
        loc_abs = sqrtf(re * re + im * im);
        loc_phi = fabsf(atan2f(im, re)) * P;
    }
#pragma unroll
    for (int off = 32; off > 0; off >>= 1) {
        loc_abs += __shfl_down(loc_abs, off, 64);
        loc_phi += __shfl_down(loc_phi, off, 64);
    }
    if (t == 0) {
        const float den = sqrtf(norm2[mu]);
        contrib[b] = loc_abs / den + loc_phi;
    }
}

// ---------------------------------------------------------------------------
// Kernel E: deterministic final reduction (f64 accum), E -> out[2048]
// ---------------------------------------------------------------------------
__global__ __launch_bounds__(256) void finalize_kernel(
    const float* __restrict__ contrib,
    float* __restrict__ out)
{
    __shared__ double sm[4];
    double acc = 0.0;
    for (int i = threadIdx.x; i < BD; i += 256) acc += (double)contrib[i];
#pragma unroll
    for (int off = 32; off > 0; off >>= 1) acc += __shfl_down(acc, off, 64);
    if ((threadIdx.x & 63) == 0) sm[threadIdx.x >> 6] = acc;
    __syncthreads();
    if (threadIdx.x == 0) {
        double s = sm[0] + sm[1] + sm[2] + sm[3];
        out[BD] = (float)(-s);
    }
}

// ---------------------------------------------------------------------------
// Fallback (round-5 passing path) if ws_size is too small
// ---------------------------------------------------------------------------
__global__ __launch_bounds__(1024) void scores_kernel_fb(
    const float* __restrict__ W,
    const float* __restrict__ pos,
    const int*   __restrict__ ids,
    float* __restrict__ out,
    int* __restrict__ mu_int)
{
    __shared__ int   s_id[WDIM];
    __shared__ float s_c[WDIM];
    __shared__ float s_s[WDIM];
    __shared__ float r_val[16];
    __shared__ int   r_idx[16];

    const int b = blockIdx.x;
    const int t = threadIdx.x;

    if (t < WDIM) {
        s_id[t] = ids[b * WDIM + t];
        const float pf = __fmul_rn(pos[b * WDIM + t], PI_F);
        s_c[t] = cosf(pf);
        s_s[t] = sinf(pf);
    }
    __syncthreads();

    const float* Wk = W + (size_t)t * (VD * 2);
    float phi[WDIM];
#pragma unroll
    for (int w = 0; w < WDIM; ++w) {
        const float2 g = *reinterpret_cast<const float2*>(Wk + 2 * (size_t)s_id[w]);
        const float c = s_c[w], s = s_s[w];
        const float mag = hypotf(g.x, g.y);
        const float re = __fadd_rn(__fmul_rn(g.x, c), __fmul_rn(g.y, s));
        const float im = __fsub_rn(__fmul_rn(g.y, c), __fmul_rn(g.x, s));
        phi[w] = __fadd_rn(mag, fabsf(atan2f(im, re)));
    }
    const float r0 = __fadd_rn(phi[0], phi[8]);
    const float r1 = __fadd_rn(phi[1], phi[9]);
    const float r2 = __fadd_rn(phi[2], phi[10]);
    const float r3 = __fadd_rn(phi[3], phi[11]);
    const float r4 = __fadd_rn(phi[4], phi[12]);
    const float r5 = __fadd_rn(phi[5], phi[13]);
    const float r6 = __fadd_rn(phi[6], phi[14]);
    const float r7 = __fadd_rn(phi[7], phi[15]);
    float score = __fadd_rn(__fadd_rn(__fadd_rn(r0, r1), __fadd_rn(r2, r3)),
                            __fadd_rn(__fadd_rn(r4, r5), __fadd_rn(r6, r7)));
    score = __fadd_rn(score, phi[16]);
    score = __fadd_rn(score, phi[17]);
    score = __fadd_rn(score, phi[18]);
    score = __fadd_rn(score, phi[19]);

    float v = score; int vi = t;
#pragma unroll
    for (int off = 32; off > 0; off >>= 1) {
        float ov = __shfl_down(v, off, 64);
        int   oi = __shfl_down(vi, off, 64);
        if (ov > v || (ov == v && oi < vi)) { v = ov; vi = oi; }
    }
    if ((t & 63) == 0) { r_val[t >> 6] = v; r_idx[t >> 6] = vi; }
    __syncthreads();
    if (t == 0) {
        float bv = r_val[0]; int bi = r_idx[0];
#pragma unroll
        for (int i = 1; i < 16; ++i) {
            if (r_val[i] > bv || (r_val[i] == bv && r_idx[i] < bi)) {
                bv = r_val[i]; bi = r_idx[i];
            }
        }
        mu_int[b] = bi;
        out[b] = (float)bi;
    }
}

__global__ __launch_bounds__(512) void norm_kernel_fb(
    const float* __restrict__ W,
    float* __restrict__ norm2)
{
    const int k = blockIdx.x;
    const float4* row = reinterpret_cast<const float4*>(W + (size_t)k * (VD * 2));
    const int n4 = (VD * 2) / 4;
    float acc = 0.0f;
    for (int i = threadIdx.x; i < n4; i += 512) {
        float4 v = row[i];
        acc += v.x * v.x + v.y * v.y + v.z * v.z + v.w * v.w;
    }
    __shared__ float sm[8];
#pragma unroll
    for (int off = 32; off > 0; off >>= 1) acc += __shfl_down(acc, off, 64);
    if ((threadIdx.x & 63) == 0) sm[threadIdx.x >> 6] = acc;
    __syncthreads();
    if (threadIdx.x == 0) {
        float s = 0.0f;
#pragma unroll
        for (int i = 0; i < 8; ++i) s += sm[i];
        norm2[k] = s;
    }
}

extern "C" void kernel_launch(void* const* d_in, const int* in_sizes, int n_in,
                              void* d_out, int out_size, void* d_ws, size_t ws_size,
                              hipStream_t stream) {
    const float* W   = (const float*)d_in[0];  // (K, V, 2) fp32
    const float* Ps  = (const float*)d_in[1];  // (B, WD) fp32
    const float* pos = (const float*)d_in[2];  // (B, WD) fp32
    const int*   ids = (const int*)d_in[3];    // (B, WD) int32

    float* out = (float*)d_out;                // float32[2049]

    // ws layout
    float2*       cst     = (float2*)d_ws;                         // WD*BD float2
    unsigned int* idp     = (unsigned int*)(cst + WDIM * BD);      // (WD/2)*BD u32
    float*        norm2   = (float*)(idp + (WDIM / 2) * BD);       // KD
    float*        contrib = norm2 + KD;                            // BD
    int*          mu_int  = (int*)(contrib + BD);                  // BD
    float*        scores  = (float*)(mu_int + BD);                 // KD*BD
    const size_t need = (size_t)(WDIM * BD * 2 + (WDIM / 2) * BD + KD + 2 * BD) * 4
                      + (size_t)KD * BD * 4;

    if (ws_size >= need) {
        prep_kernel<<<(BD + 255) / 256, 256, 0, stream>>>(pos, ids, cst, idp);
        row_kernel<<<KD * 2, 1024, 0, stream>>>(W, idp, cst, norm2, scores);
        argmax_kernel<<<BD / 256, 256, 0, stream>>>(scores, out, mu_int);
    } else {
        scores_kernel_fb<<<BD, 1024, 0, stream>>>(W, pos, ids, out, mu_int);
        norm_kernel_fb<<<KD, 512, 0, stream>>>(W, norm2);
    }
    e_kernel<<<BD, 64, 0, stream>>>(W, Ps, pos, ids, mu_int, norm2, contrib);
    finalize_kernel<<<1, 256, 0, stream>>>(contrib, out);
}

// Round 11
// 268.815 us; speedup vs baseline: 2.9827x; 1.2818x over previous
//
#include <hip/hip_runtime.h>
#include <hip/hip_bf16.h>
#include <math.h>

#define KD 1024
#define VD 50000
#define BD 2048
#define WDIM 20
#define THRV 1e-10f
#define PI_F 3.14159274101257324f  /* 0x40490FDB — f32(pi) */

#define CH 8192            /* complex elements per chunk (64 KB LDS) */
#define NCH 7              /* 6 full chunks + tail */
#define TAILC 848          /* 50000 - 6*8192 */

// d_out is FLOAT32[2049]: [0..2048) = mu (as float), [2048] = E.
//
// LESSON (r8-r10): inline-asm vmcnt/barrier + global_load_lds blocks AGPR
// placement of per-thread arrays -> 200B/thread scratch (WRITE_SIZE 419-656MB).
// Round 6's plain-HIP version held 80 floats/thread in AGPRs (WRITE 8.2MB).
// So: plain HIP only; overlap via 2 blocks/CU (TLP), not via asm pipelining.

// ---------------------------------------------------------------------------
// Kernel P: b-minor tables. cst[w][b] = (cos,sin)(pi*pos[b][w]);
// idp[j][b] = ids[b][2j] | ids[b][2j+1]<<16. Same trig ops as passing rounds.
// ---------------------------------------------------------------------------
__global__ __launch_bounds__(256) void prep_kernel(
    const float* __restrict__ pos,
    const int*   __restrict__ ids,
    float2* __restrict__ cst,
    unsigned int* __restrict__ idp)
{
    const int b = blockIdx.x * 256 + threadIdx.x;
    if (b >= BD) return;
    int idv[WDIM];
#pragma unroll
    for (int w = 0; w < WDIM; ++w) {
        idv[w] = ids[b * WDIM + w];
        const float pf = __fmul_rn(pos[b * WDIM + w], PI_F);
        cst[w * BD + b] = make_float2(cosf(pf), sinf(pf));
    }
#pragma unroll
    for (int j = 0; j < WDIM / 2; ++j)
        idp[j * BD + b] = (unsigned int)idv[2 * j] |
                          ((unsigned int)idv[2 * j + 1] << 16);
}

// ---------------------------------------------------------------------------
// Kernel B: grid 4096 = (row k) x (quarter of B). 512 threads, 64KB LDS ->
// 2 blocks/CU: one block streams (HBM) while the other matches (VALU/LDS).
// Each thread owns ONE b (40-float g-state -> AGPRs, plain HIP).
// XCD swizzle: 4 sibling quarters of row k adjacent on the same XCD -> the
// row is HBM-fetched ~once, siblings hit L2 (validated r10: FETCH 430->359MB).
// Score math bit-identical to rounds 5-10 (pairwise-8, _rn ops).
// ---------------------------------------------------------------------------
__global__ __launch_bounds__(512, 4) void quarter_kernel(
    const float* __restrict__ W,
    const unsigned int* __restrict__ idp,
    const float2* __restrict__ cst,
    float* __restrict__ norm2,
    float* __restrict__ scores)   // [KD][BD]
{
    __shared__ __align__(16) float chunk[CH * 2];   // 64 KB
    __shared__ float sm[8];

    const int t = threadIdx.x;
    // swizzle: xcd = g&7; slot = g>>3; k = xcd + 8*(slot>>2); quarter = slot&3
    const int g       = blockIdx.x;
    const int slot    = g >> 3;
    const int k       = (g & 7) + 8 * (slot >> 2);
    const int quarter = slot & 3;
    const int b       = quarter * 512 + t;

    const float* Wk = W + (size_t)k * (VD * 2);

    // packed ids for this thread's single b
    unsigned int idreg[WDIM / 2];
#pragma unroll
    for (int j = 0; j < WDIM / 2; ++j) idreg[j] = idp[j * BD + b];

    float gx[WDIM], gy[WDIM];
#pragma unroll
    for (int w = 0; w < WDIM; ++w) { gx[w] = 0.f; gy[w] = 0.f; }

    float nacc = 0.0f;

    for (int c = 0; c < NCH; ++c) {
        const bool istail = (c == NCH - 1);
        const int nf4 = istail ? (TAILC * 2) / 4 : (CH * 2) / 4;

        __syncthreads();   // previous chunk's readers done
        const float4* src = reinterpret_cast<const float4*>(Wk + (size_t)c * (CH * 2));
        float4* dst = reinterpret_cast<float4*>(chunk);
#pragma unroll
        for (int j = 0; j < 8; ++j) {
            const int i = t + j * 512;
            if (i < nf4) {
                const float4 v = src[i];
                dst[i] = v;
                nacc += v.x * v.x + v.y * v.y + v.z * v.z + v.w * v.w;
            }
        }
        __syncthreads();   // chunk visible

        // ---- predicated match (one b per thread) ----
        const int lo = c * CH;
        const unsigned lim = istail ? TAILC : CH;
#pragma unroll
        for (int w = 0; w < WDIM; ++w) {
            const int id = (int)((idreg[w >> 1] >> ((w & 1) * 16)) & 0xFFFFu);
            const unsigned off = (unsigned)(id - lo);
            if (off < lim) {
                gx[w] = chunk[2 * off];
                gy[w] = chunk[2 * off + 1];
            }
        }
    }

    // ---- norm2 reduce (full row per block; write once from quarter 0) ----
#pragma unroll
    for (int off = 32; off > 0; off >>= 1) nacc += __shfl_down(nacc, off, 64);
    if ((t & 63) == 0) sm[t >> 6] = nacc;
    __syncthreads();
    if (t == 0 && quarter == 0) {
        float s = 0.0f;
#pragma unroll
        for (int i = 0; i < 8; ++i) s += sm[i];
        norm2[k] = s;
    }

    // ---- score math (exact numpy pairwise-8 order) ----
    {
        float phi[WDIM];
#pragma unroll
        for (int w = 0; w < WDIM; ++w) {
            const float2 cs = cst[w * BD + b];
            const float x = gx[w], y = gy[w];
            const float mag = hypotf(x, y);
            const float re  = __fadd_rn(__fmul_rn(x, cs.x), __fmul_rn(y, cs.y));
            const float im  = __fsub_rn(__fmul_rn(y, cs.x), __fmul_rn(x, cs.y));
            phi[w] = __fadd_rn(mag, fabsf(atan2f(im, re)));
        }
        const float r0 = __fadd_rn(phi[0], phi[8]);
        const float r1 = __fadd_rn(phi[1], phi[9]);
        const float r2 = __fadd_rn(phi[2], phi[10]);
        const float r3 = __fadd_rn(phi[3], phi[11]);
        const float r4 = __fadd_rn(phi[4], phi[12]);
        const float r5 = __fadd_rn(phi[5], phi[13]);
        const float r6 = __fadd_rn(phi[6], phi[14]);
        const float r7 = __fadd_rn(phi[7], phi[15]);
        float score = __fadd_rn(__fadd_rn(__fadd_rn(r0, r1), __fadd_rn(r2, r3)),
                                __fadd_rn(__fadd_rn(r4, r5), __fadd_rn(r6, r7)));
        score = __fadd_rn(score, phi[16]);
        score = __fadd_rn(score, phi[17]);
        score = __fadd_rn(score, phi[18]);
        score = __fadd_rn(score, phi[19]);
        scores[(size_t)k * BD + b] = score;
    }
}

// ---------------------------------------------------------------------------
// Kernel C: argmax over k per batch (coalesced). Strict >, tie -> smallest k.
// ---------------------------------------------------------------------------
__global__ __launch_bounds__(256) void argmax_kernel(
    const float* __restrict__ scores,
    float* __restrict__ out,
    int*   __restrict__ mu_int)
{
    const int b = blockIdx.x * 256 + threadIdx.x;
    float best = -3.402823466e+38f;
    int   bi   = 0;
    for (int k = 0; k < KD; ++k) {
        const float v = scores[(size_t)k * BD + b];
        if (v > best) { best = v; bi = k; }
    }
    mu_int[b] = bi;
    out[b] = (float)bi;
}

// ---------------------------------------------------------------------------
// Kernel D: per-batch energy contribution
// ---------------------------------------------------------------------------
__global__ __launch_bounds__(64) void e_kernel(
    const float* __restrict__ W,
    const float* __restrict__ Ps,
    const float* __restrict__ pos,
    const int*   __restrict__ ids,
    const int*   __restrict__ mu_int,
    const float* __restrict__ norm2,
    float* __restrict__ contrib)
{
    const int b = blockIdx.x;
    const int t = threadIdx.x;
    const int mu = mu_int[b];
    const float* Wm = W + (size_t)mu * (VD * 2);

    float loc_abs = 0.0f, loc_phi = 0.0f;
    if (t < WDIM) {
        const int id = ids[b * WDIM + t];
        const float P = Ps[b * WDIM + t];
        const float pf = __fmul_rn(pos[b * WDIM + t], PI_F);
        const float c = cosf(pf), s = sinf(pf);
        const float2 g = *reinterpret_cast<const float2*>(Wm + 2 * (size_t)id);
        float re = P * (g.x * c + g.y * s);
        float im = P * (g.y * c - g.x * s);
        if (re < THRV && re > -THRV) re = THRV;
        if (im < THRV && im > -THRV) im = THRV;
        loc_abs = sqrtf(re * re + im * im);
        loc_phi = fabsf(atan2f(im, re)) * P;
    }
#pragma unroll
    for (int off = 32; off > 0; off >>= 1) {
        loc_abs += __shfl_down(loc_abs, off, 64);
        loc_phi += __shfl_down(loc_phi, off, 64);
    }
    if (t == 0) {
        const float den = sqrtf(norm2[mu]);
        contrib[b] = loc_abs / den + loc_phi;
    }
}

// ---------------------------------------------------------------------------
// Kernel E: deterministic final reduction (f64 accum), E -> out[2048]
// ---------------------------------------------------------------------------
__global__ __launch_bounds__(256) void finalize_kernel(
    const float* __restrict__ contrib,
    float* __restrict__ out)
{
    __shared__ double sm[4];
    double acc = 0.0;
    for (int i = threadIdx.x; i < BD; i += 256) acc += (double)contrib[i];
#pragma unroll
    for (int off = 32; off > 0; off >>= 1) acc += __shfl_down(acc, off, 64);
    if ((threadIdx.x & 63) == 0) sm[threadIdx.x >> 6] = acc;
    __syncthreads();
    if (threadIdx.x == 0) {
        double s = sm[0] + sm[1] + sm[2] + sm[3];
        out[BD] = (float)(-s);
    }
}

// ---------------------------------------------------------------------------
// Fallback (round-5 passing path) if ws_size is too small
// ---------------------------------------------------------------------------
__global__ __launch_bounds__(1024) void scores_kernel_fb(
    const float* __restrict__ W,
    const float* __restrict__ pos,
    const int*   __restrict__ ids,
    float* __restrict__ out,
    int* __restrict__ mu_int)
{
    __shared__ int   s_id[WDIM];
    __shared__ float s_c[WDIM];
    __shared__ float s_s[WDIM];
    __shared__ float r_val[16];
    __shared__ int   r_idx[16];

    const int b = blockIdx.x;
    const int t = threadIdx.x;

    if (t < WDIM) {
        s_id[t] = ids[b * WDIM + t];
        const float pf = __fmul_rn(pos[b * WDIM + t], PI_F);
        s_c[t] = cosf(pf);
        s_s[t] = sinf(pf);
    }
    __syncthreads();

    const float* Wk = W + (size_t)t * (VD * 2);
    float phi[WDIM];
#pragma unroll
    for (int w = 0; w < WDIM; ++w) {
        const float2 g = *reinterpret_cast<const float2*>(Wk + 2 * (size_t)s_id[w]);
        const float c = s_c[w], s = s_s[w];
        const float mag = hypotf(g.x, g.y);
        const float re = __fadd_rn(__fmul_rn(g.x, c), __fmul_rn(g.y, s));
        const float im = __fsub_rn(__fmul_rn(g.y, c), __fmul_rn(g.x, s));
        phi[w] = __fadd_rn(mag, fabsf(atan2f(im, re)));
    }
    const float r0 = __fadd_rn(phi[0], phi[8]);
    const float r1 = __fadd_rn(phi[1], phi[9]);
    const float r2 = __fadd_rn(phi[2], phi[10]);
    const float r3 = __fadd_rn(phi[3], phi[11]);
    const float r4 = __fadd_rn(phi[4], phi[12]);
    const float r5 = __fadd_rn(phi[5], phi[13]);
    const float r6 = __fadd_rn(phi[6], phi[14]);
    const float r7 = __fadd_rn(phi[7], phi[15]);
    float score = __fadd_rn(__fadd_rn(__fadd_rn(r0, r1), __fadd_rn(r2, r3)),
                            __fadd_rn(__fadd_rn(r4, r5), __fadd_rn(r6, r7)));
    score = __fadd_rn(score, phi[16]);
    score = __fadd_rn(score, phi[17]);
    score = __fadd_rn(score, phi[18]);
    score = __fadd_rn(score, phi[19]);

    float v = score; int vi = t;
#pragma unroll
    for (int off = 32; off > 0; off >>= 1) {
        float ov = __shfl_down(v, off, 64);
        int   oi = __shfl_down(vi, off, 64);
        if (ov > v || (ov == v && oi < vi)) { v = ov; vi = oi; }
    }
    if ((t & 63) == 0) { r_val[t >> 6] = v; r_idx[t >> 6] = vi; }
    __syncthreads();
    if (t == 0) {
        float bv = r_val[0]; int bi = r_idx[0];
#pragma unroll
        for (int i = 1; i < 16; ++i) {
            if (r_val[i] > bv || (r_val[i] == bv && r_idx[i] < bi)) {
                bv = r_val[i]; bi = r_idx[i];
            }
        }
        mu_int[b] = bi;
        out[b] = (float)bi;
    }
}

__global__ __launch_bounds__(512) void norm_kernel_fb(
    const float* __restrict__ W,
    float* __restrict__ norm2)
{
    const int k = blockIdx.x;
    const float4* row = reinterpret_cast<const float4*>(W + (size_t)k * (VD * 2));
    const int n4 = (VD * 2) / 4;
    float acc = 0.0f;
    for (int i = threadIdx.x; i < n4; i += 512) {
        float4 v = row[i];
        acc += v.x * v.x + v.y * v.y + v.z * v.z + v.w * v.w;
    }
    __shared__ float sm[8];
#pragma unroll
    for (int off = 32; off > 0; off >>= 1) acc += __shfl_down(acc, off, 64);
    if ((threadIdx.x & 63) == 0) sm[threadIdx.x >> 6] = acc;
    __syncthreads();
    if (threadIdx.x == 0) {
        float s = 0.0f;
#pragma unroll
        for (int i = 0; i < 8; ++i) s += sm[i];
        norm2[k] = s;
    }
}

extern "C" void kernel_launch(void* const* d_in, const int* in_sizes, int n_in,
                              void* d_out, int out_size, void* d_ws, size_t ws_size,
                              hipStream_t stream) {
    const float* W   = (const float*)d_in[0];  // (K, V, 2) fp32
    const float* Ps  = (const float*)d_in[1];  // (B, WD) fp32
    const float* pos = (const float*)d_in[2];  // (B, WD) fp32
    const int*   ids = (const int*)d_in[3];    // (B, WD) int32

    float* out = (float*)d_out;                // float32[2049]

    // ws layout
    float2*       cst     = (float2*)d_ws;                         // WD*BD float2
    unsigned int* idp     = (unsigned int*)(cst + WDIM * BD);      // (WD/2)*BD u32
    float*        norm2   = (float*)(idp + (WDIM / 2) * BD);       // KD
    float*        contrib = norm2 + KD;                            // BD
    int*          mu_int  = (int*)(contrib + BD);                  // BD
    float*        scores  = (float*)(mu_int + BD);                 // KD*BD
    const size_t need = (size_t)(WDIM * BD * 2 + (WDIM / 2) * BD + KD + 2 * BD) * 4
                      + (size_t)KD * BD * 4;

    if (ws_size >= need) {
        prep_kernel<<<(BD + 255) / 256, 256, 0, stream>>>(pos, ids, cst, idp);
        quarter_kernel<<<KD * 4, 512, 0, stream>>>(W, idp, cst, norm2, scores);
        argmax_kernel<<<BD / 256, 256, 0, stream>>>(scores, out, mu_int);
    } else {
        scores_kernel_fb<<<BD, 1024, 0, stream>>>(W, pos, ids, out, mu_int);
        norm_kernel_fb<<<KD, 512, 0, stream>>>(W, norm2);
    }
    e_kernel<<<BD, 64, 0, stream>>>(W, Ps, pos, ids, mu_int, norm2, contrib);
    finalize_kernel<<<1, 256, 0, stream>>>(contrib, out);
}